// Round 5
// baseline (191.005 us; speedup 1.0000x reference)
//
#include <hip/hip_runtime.h>
#include <math.h>

// Shapes (fixed by the problem)
#define Hn 8
#define Sn 1024
#define Dn 64
#define KG 10

// Bias tables: dist in [0,10), energy in [0,5)
#define TN 2048
#define RD 10.25f
#define RE 5.125f

// k-split factor: grid (S/16, H, KS) = 2048 blocks; with 16.4 KB LDS and
// <=64 VGPR all 8 blocks/CU are resident -> 32 waves/CU (hardware max).
#define KS 4
// partials per q-row: KS k-splits x 4 waves
#define NP (KS * 4)

typedef __attribute__((ext_vector_type(8))) short bf16x8;
typedef __attribute__((ext_vector_type(4))) float f32x4;
typedef unsigned short u16;
typedef unsigned int u32;

__device__ inline float bf2f(u16 u) {
    union { u32 i; float f; } v;
    v.i = ((u32)u) << 16;
    return v.f;
}

__device__ inline u16 f2bf(float f) {
    union { float f; u32 i; } v;
    v.f = f;
    u32 i = v.i;
    return (u16)((i + 0x7FFFu + ((i >> 16) & 1u)) >> 16);   // RNE
}

// ---------------------------------------------------------------------------
// RBF (10 gaussians) -> 10x10 MLP (exact gelu) -> scalar, all f32.
// ---------------------------------------------------------------------------
__device__ float bias_eval(float x,
                           const float* __restrict__ mu, const float* __restrict__ sg,
                           const float* __restrict__ bb,
                           const float* __restrict__ W1, const float* __restrict__ b1,
                           const float* __restrict__ W2, const float* __restrict__ b2) {
    const float inv_s2pi = 0.39894228040143267794f;
    float psi[KG];
#pragma unroll
    for (int k = 0; k < KG; k++) {
        float s = sg[k];
        float z = (x + bb[k] - mu[k]) / s;
        psi[k] = __expf(-0.5f * z * z) * (inv_s2pi / s);
    }
    float out = b2[0];
#pragma unroll
    for (int l = 0; l < KG; l++) {
        float a = b1[l];
#pragma unroll
        for (int k = 0; k < KG; k++) a += psi[k] * W1[l * KG + k];
        float g = 0.5f * a * (1.0f + erff(a * 0.70710678118654752440f));
        out += g * W2[l];
    }
    return out;
}

// ---------------------------------------------------------------------------
// Fused prepass:
//  ids [0, 2*TN)                 : bias interp tables (bf16 value | bf16 delta)
//  ids [2*TN, 2*TN+262144)       : Q,K f32 -> bf16 (float4 granularity)
//  ids [2*TN+262144, +524288)    : V -> bf16, transposed [h][d][s'] with the
//                                  k-permutation matching the P register order
// ---------------------------------------------------------------------------
#define QK4 262144              // (2*Hn*Sn*Dn)/4
#define VTN 524288              // Hn*Sn*Dn

__global__ __launch_bounds__(256) void prep_kernel(
    const float* __restrict__ Q, const float* __restrict__ K, const float* __restrict__ V,
    const float* __restrict__ muD, const float* __restrict__ sgD, const float* __restrict__ bD,
    const float* __restrict__ muE, const float* __restrict__ sgE, const float* __restrict__ bE,
    const float* __restrict__ W1, const float* __restrict__ b1,
    const float* __restrict__ W2, const float* __restrict__ b2,
    u32* __restrict__ tab, u16* __restrict__ Qb, u16* __restrict__ Kb, u16* __restrict__ VTi)
{
    int id = blockIdx.x * 256 + threadIdx.x;
    if (id < 2 * TN) {
        int which = (id >= TN);
        int idx = id & (TN - 1);
        float h = (which ? RE : RD) / (float)TN;
        float x0 = idx * h;
        float v0, v1;
        if (which) {
            v0 = bias_eval(x0,     muE, sgE, bE, W1, b1, W2, b2);
            v1 = bias_eval(x0 + h, muE, sgE, bE, W1, b1, W2, b2);
        } else {
            v0 = bias_eval(x0,     muD, sgD, bD, W1, b1, W2, b2);
            v1 = bias_eval(x0 + h, muD, sgD, bD, W1, b1, W2, b2);
        }
        tab[id] = (u32)f2bf(v0) | ((u32)f2bf(v1 - v0) << 16);
    } else if (id < 2 * TN + QK4) {
        int i = id - 2 * TN;
        int arr = i >> 17;          // 0 = Q, 1 = K
        i &= (1 << 17) - 1;
        float4 v = ((const float4*)(arr ? K : Q))[i];
        ushort4 o;
        o.x = f2bf(v.x); o.y = f2bf(v.y); o.z = f2bf(v.z); o.w = f2bf(v.w);
        ((ushort4*)(arr ? Kb : Qb))[i] = o;
    } else if (id < 2 * TN + QK4 + VTN) {
        int g = id - (2 * TN + QK4);
        int h = g >> 16;
        int d = (g >> 10) & 63;
        int s = g & 1023;
        int t = s >> 5, q = (s >> 3) & 3, j = s & 7;
        int src_s = (t << 5) + (q << 2) + (j & 3) + ((j >> 2) << 4);
        VTi[g] = f2bf(V[(((size_t)h << 10) + src_s) * Dn + d]);
    }
}

__device__ inline float lerp_tab(const u32* __restrict__ st, float x, float invh) {
    float tf = x * invh;
    int i = (int)tf;
    i = max(0, min(i, TN - 1));
    float fr = tf - (float)i;
    u32 p = st[i];
    return fmaf(bf2f((u16)(p >> 16)), fr, bf2f((u16)p));
}

// ---------------------------------------------------------------------------
// Fused flash attention, S^T formulation, k-split across blockIdx.z.
// MAX-RESIDENCY VERSION: no cross-wave combine in-block -> LDS is only the
// 16 KB bias table -> 8 blocks/CU resident (32 waves, HW max) with
// launch_bounds(256,8) (VGPR<=64; measured 60 before). All 2048 blocks are
// co-resident, so each CU runs 8 independent 2-tile chains concurrently --
// the pure-TLP fix for the measured latency-chain bound (R4: L3-warm replay
// at identical 43us proved time is latency, not BW).
// Each WAVE writes its own unnormalized partial (m, l, U) to workspace;
// combine_kernel merges the NP=16 partials per q-row.
// ---------------------------------------------------------------------------
__global__ __launch_bounds__(256, 8) void attn_kernel(
    const u16* __restrict__ Qb, const u16* __restrict__ Kb, const u16* __restrict__ VTi,
    const float* __restrict__ Dm, const float* __restrict__ Em, const int* __restrict__ Mk,
    const u32* __restrict__ gtab,
    float* __restrict__ Up, float* __restrict__ Mp, float* __restrict__ Lp)
{
    __shared__ __align__(16) u32 sTab[2 * TN];      // 16 KB (only LDS use)

    const int tid = threadIdx.x;
    {   // stage tables: 1024 uint4 over 256 threads
        const uint4* g4 = (const uint4*)gtab;
        uint4* s4 = (uint4*)sTab;
#pragma unroll
        for (int i = 0; i < 4; i++) s4[tid + 256 * i] = g4[tid + 256 * i];
    }
    __syncthreads();

    const int h    = blockIdx.y;
    const int qb   = blockIdx.x;
    const int ks   = blockIdx.z;
    const int q0   = qb * 16;
    const int wave = tid >> 6;
    const int lane = tid & 63;
    const int quad = lane >> 4;
    const int l16  = lane & 15;

    const u16* Qh = Qb  + (size_t)h * Sn * Dn;
    const u16* Kh = Kb  + (size_t)h * Sn * Dn;
    const u16* Vh = VTi + (size_t)h * Dn * Sn;
    const float* Dh = Dm + (size_t)h * Sn * Sn + (size_t)(q0 + l16) * Sn;
    const float* Eh = Em + (size_t)h * Sn * Sn + (size_t)(q0 + l16) * Sn;
    const int*   Mh = Mk + (size_t)h * Sn * Sn + (size_t)(q0 + l16) * Sn;
    const float invhD = (float)TN / RD;
    const float invhE = (float)TN / RE;
    const float scale = 0.08838834764831845f;       // 1/sqrt(2*64)

    // Persistent Q B-fragments: B[n=l16][k=quad*8+j], k = d-dim
    const bf16x8 bQ0 = *(const bf16x8*)(Qh + (q0 + l16) * Dn + quad * 8);
    const bf16x8 bQ1 = *(const bf16x8*)(Qh + (q0 + l16) * Dn + 32 + quad * 8);

    f32x4 O0 = {0.f, 0.f, 0.f, 0.f}, O1 = O0, O2 = O0, O3 = O0;
    float m_run = -1e30f, l_run = 0.f;

    for (int t = 0; t < 2; t++) {
        const int k0 = ks * 256 + wave * 64 + t * 32;

        const float4 Dv0 = *(const float4*)(Dh + k0 + quad * 4);
        const float4 Dv1 = *(const float4*)(Dh + k0 + 16 + quad * 4);
        const float4 Ev0 = *(const float4*)(Eh + k0 + quad * 4);
        const float4 Ev1 = *(const float4*)(Eh + k0 + 16 + quad * 4);
        const int4   Mv0 = *(const int4*)(Mh + k0 + quad * 4);
        const int4   Mv1 = *(const int4*)(Mh + k0 + 16 + quad * 4);

        const u16* kr = Kh + (size_t)(k0 + l16) * Dn + quad * 8;
        const bf16x8 aK00 = *(const bf16x8*)(kr);
        const bf16x8 aK01 = *(const bf16x8*)(kr + 32);
        const bf16x8 aK10 = *(const bf16x8*)(kr + 16 * Dn);
        const bf16x8 aK11 = *(const bf16x8*)(kr + 16 * Dn + 32);

        const u16* vr = Vh + k0 + quad * 8;
        const bf16x8 bV0 = *(const bf16x8*)(vr + (size_t)(l16)      * Sn);
        const bf16x8 bV1 = *(const bf16x8*)(vr + (size_t)(16 + l16) * Sn);
        const bf16x8 bV2 = *(const bf16x8*)(vr + (size_t)(32 + l16) * Sn);
        const bf16x8 bV3 = *(const bf16x8*)(vr + (size_t)(48 + l16) * Sn);

        f32x4 s0 = {0.f, 0.f, 0.f, 0.f}, s1 = s0;
        s0 = __builtin_amdgcn_mfma_f32_16x16x32_bf16(aK00, bQ0, s0, 0, 0, 0);
        s0 = __builtin_amdgcn_mfma_f32_16x16x32_bf16(aK01, bQ1, s0, 0, 0, 0);
        s1 = __builtin_amdgcn_mfma_f32_16x16x32_bf16(aK10, bQ0, s1, 0, 0, 0);
        s1 = __builtin_amdgcn_mfma_f32_16x16x32_bf16(aK11, bQ1, s1, 0, 0, 0);

        const float dv0[4] = {Dv0.x, Dv0.y, Dv0.z, Dv0.w};
        const float dv1[4] = {Dv1.x, Dv1.y, Dv1.z, Dv1.w};
        const float ev0[4] = {Ev0.x, Ev0.y, Ev0.z, Ev0.w};
        const float ev1[4] = {Ev1.x, Ev1.y, Ev1.z, Ev1.w};
        const int   mv0[4] = {Mv0.x, Mv0.y, Mv0.z, Mv0.w};
        const int   mv1[4] = {Mv1.x, Mv1.y, Mv1.z, Mv1.w};

        float sc0[4], sc1[4];
#pragma unroll
        for (int r = 0; r < 4; r++) {
            float v0 = s0[r] * scale + lerp_tab(sTab, dv0[r], invhD)
                                     + lerp_tab(sTab + TN, ev0[r], invhE);
            v0 = fminf(fmaxf(v0, -80.f), 80.f);
            sc0[r] = (mv0[r] == 0) ? -1e9f : v0;
            float v1 = s1[r] * scale + lerp_tab(sTab, dv1[r], invhD)
                                     + lerp_tab(sTab + TN, ev1[r], invhE);
            v1 = fminf(fmaxf(v1, -80.f), 80.f);
            sc1[r] = (mv1[r] == 0) ? -1e9f : v1;
        }

        // row max: local over 8 values, then across quads (2 shuffles)
        float mloc = fmaxf(fmaxf(fmaxf(sc0[0], sc0[1]), fmaxf(sc0[2], sc0[3])),
                           fmaxf(fmaxf(sc1[0], sc1[1]), fmaxf(sc1[2], sc1[3])));
        mloc = fmaxf(mloc, __shfl_xor(mloc, 16, 64));
        mloc = fmaxf(mloc, __shfl_xor(mloc, 32, 64));

        const float mn = fmaxf(m_run, mloc);
        const float al = __expf(m_run - mn);
        m_run = mn;

        float p0[4], p1[4], ll = 0.f;
#pragma unroll
        for (int r = 0; r < 4; r++) {
            p0[r] = __expf(sc0[r] - mn);
            p1[r] = __expf(sc1[r] - mn);
            ll += p0[r] + p1[r];
        }
        ll += __shfl_xor(ll, 16, 64);
        ll += __shfl_xor(ll, 32, 64);
        l_run = l_run * al + ll;

        // P A-fragment straight from registers (k-order matches permuted V)
        bf16x8 aP;
#pragma unroll
        for (int r = 0; r < 4; r++) {
            aP[r]     = (short)f2bf(p0[r]);
            aP[4 + r] = (short)f2bf(p1[r]);
        }

        // O rescale: alpha for row quad*4+r lives in lane (quad*4+r)
        const float a0 = __shfl(al, quad * 4 + 0, 64);
        const float a1 = __shfl(al, quad * 4 + 1, 64);
        const float a2 = __shfl(al, quad * 4 + 2, 64);
        const float a3 = __shfl(al, quad * 4 + 3, 64);
        O0[0] *= a0; O0[1] *= a1; O0[2] *= a2; O0[3] *= a3;
        O1[0] *= a0; O1[1] *= a1; O1[2] *= a2; O1[3] *= a3;
        O2[0] *= a0; O2[1] *= a1; O2[2] *= a2; O2[3] *= a3;
        O3[0] *= a0; O3[1] *= a1; O3[2] *= a2; O3[3] *= a3;

        O0 = __builtin_amdgcn_mfma_f32_16x16x32_bf16(aP, bV0, O0, 0, 0, 0);
        O1 = __builtin_amdgcn_mfma_f32_16x16x32_bf16(aP, bV1, O1, 0, 0, 0);
        O2 = __builtin_amdgcn_mfma_f32_16x16x32_bf16(aP, bV2, O2, 0, 0, 0);
        O3 = __builtin_amdgcn_mfma_f32_16x16x32_bf16(aP, bV3, O3, 0, 0, 0);
    }

    // Per-wave partial straight to workspace (no LDS, no __syncthreads):
    // O regs are [row=quad*4+r][col=vt*16+l16]; U is UNNORMALIZED.
    const int p = ks * 4 + wave;
    const size_t pg = (size_t)(h * 64 + qb) * NP + p;
    float* up = Up + pg * 16 * 64;
#pragma unroll
    for (int r = 0; r < 4; r++) {
        const int row = quad * 4 + r;
        up[row * 64 +  0 + l16] = O0[r];
        up[row * 64 + 16 + l16] = O1[r];
        up[row * 64 + 32 + l16] = O2[r];
        up[row * 64 + 48 + l16] = O3[r];
    }
    if (lane < 16) {
        Mp[pg * 16 + lane] = m_run;
        Lp[pg * 16 + lane] = l_run;
    }
}

// ---------------------------------------------------------------------------
// Merge the NP=16 partials per q-row: M = max m_i; L = sum l_i e^{m_i-M};
// out = sum U_i e^{m_i-M} / L.  131072 threads, 16 threads/row.
// ---------------------------------------------------------------------------
__global__ __launch_bounds__(256) void combine_kernel(
    const float* __restrict__ Up, const float* __restrict__ Mp,
    const float* __restrict__ Lp, float* __restrict__ out)
{
    const int g  = blockIdx.x * 256 + threadIdx.x;
    const int r  = g >> 4;                 // global row 0..8191
    const int c4 = (g & 15) * 4;
    const int h  = r >> 10;
    const int s  = r & 1023;
    const int qb = s >> 4;
    const int r16 = s & 15;
    const size_t pg0 = (size_t)(h * 64 + qb) * NP;

    float m[NP], l[NP];
#pragma unroll
    for (int k = 0; k < NP; k++) {
        m[k] = Mp[(pg0 + k) * 16 + r16];
        l[k] = Lp[(pg0 + k) * 16 + r16];
    }
    float M = m[0];
#pragma unroll
    for (int k = 1; k < NP; k++) M = fmaxf(M, m[k]);
    float f[NP], L = 0.f;
#pragma unroll
    for (int k = 0; k < NP; k++) {
        f[k] = __expf(m[k] - M);
        L += l[k] * f[k];
    }
    const float inv = 1.0f / L;

    float acc[4] = {0.f, 0.f, 0.f, 0.f};
#pragma unroll
    for (int k = 0; k < NP; k++) {
        const float4 u = *(const float4*)(Up + ((pg0 + k) * 16 + r16) * 64 + c4);
        acc[0] += u.x * f[k]; acc[1] += u.y * f[k];
        acc[2] += u.z * f[k]; acc[3] += u.w * f[k];
    }
    float4 ov = {acc[0] * inv, acc[1] * inv, acc[2] * inv, acc[3] * inv};
    *(float4*)(out + (size_t)r * Dn + c4) = ov;
}

// ---------------------------------------------------------------------------
extern "C" void kernel_launch(void* const* d_in, const int* in_sizes, int n_in,
                              void* d_out, int out_size, void* d_ws, size_t ws_size,
                              hipStream_t stream) {
    const float* Q    = (const float*)d_in[0];
    const float* K    = (const float*)d_in[1];
    const float* V    = (const float*)d_in[2];
    const float* Dm   = (const float*)d_in[3];
    const float* Em   = (const float*)d_in[4];
    const int*   Mask = (const int*)d_in[5];
    const float* muD  = (const float*)d_in[6];
    const float* sgD  = (const float*)d_in[7];
    const float* bD   = (const float*)d_in[8];
    const float* muE  = (const float*)d_in[9];
    const float* sgE  = (const float*)d_in[10];
    const float* bE   = (const float*)d_in[11];
    const float* W1   = (const float*)d_in[12];
    const float* b1   = (const float*)d_in[13];
    const float* W2   = (const float*)d_in[14];
    const float* b2   = (const float*)d_in[15];

    // ws layout: tab 16 KB | Qb/Kb/VTi 1 MB each | Up 33.5 MB | Mp,Lp 512 KB each
    u32* tab = (u32*)d_ws;
    u16* Qb  = (u16*)((char*)d_ws + 2 * TN * 4);
    u16* Kb  = Qb + (size_t)Hn * Sn * Dn;
    u16* VTi = Kb + (size_t)Hn * Sn * Dn;
    float* Up = (float*)(VTi + (size_t)Hn * Sn * Dn);
    float* Mp = Up + (size_t)Hn * 64 * NP * 16 * 64;
    float* Lp = Mp + (size_t)Hn * 64 * NP * 16;

    const int prep_threads = 2 * TN + QK4 + VTN;           // 790528
    prep_kernel<<<prep_threads / 256, 256, 0, stream>>>(
        Q, K, V, muD, sgD, bD, muE, sgE, bE, W1, b1, W2, b2,
        tab, Qb, Kb, VTi);

    dim3 grid(Sn / 16, Hn, KS);
    attn_kernel<<<grid, 256, 0, stream>>>(Qb, Kb, VTi, Dm, Em, Mask, tab,
                                          Up, Mp, Lp);

    combine_kernel<<<(Hn * Sn * 16) / 256, 256, 0, stream>>>(Up, Mp, Lp,
                                                             (float*)d_out);
}

// Round 6
// 188.737 us; speedup vs baseline: 1.0120x; 1.0120x over previous
//
#include <hip/hip_runtime.h>
#include <math.h>

// Shapes (fixed by the problem)
#define Hn 8
#define Sn 1024
#define Dn 64
#define KG 10

// Bias tables: dist in [0,10), energy in [0,5)
#define TN 2048
#define RD 10.25f
#define RE 5.125f

// k-split factor: grid (S/16, H, KS) = 2048 blocks
#define KS 4

typedef __attribute__((ext_vector_type(8))) short bf16x8;
typedef __attribute__((ext_vector_type(4))) float f32x4;
typedef _Float16 f16;
typedef __attribute__((ext_vector_type(4))) _Float16 f16x4;
typedef __attribute__((ext_vector_type(8))) _Float16 f16x8;
typedef unsigned short u16;
typedef unsigned int u32;

__device__ inline float bf2f(u16 u) {
    union { u32 i; float f; } v;
    v.i = ((u32)u) << 16;
    return v.f;
}

__device__ inline u16 f2bf(float f) {
    union { float f; u32 i; } v;
    v.f = f;
    u32 i = v.i;
    return (u16)((i + 0x7FFFu + ((i >> 16) & 1u)) >> 16);   // RNE
}

// ---------------------------------------------------------------------------
// RBF (10 gaussians) -> 10x10 MLP (exact gelu) -> scalar, all f32.
// ---------------------------------------------------------------------------
__device__ float bias_eval(float x,
                           const float* __restrict__ mu, const float* __restrict__ sg,
                           const float* __restrict__ bb,
                           const float* __restrict__ W1, const float* __restrict__ b1,
                           const float* __restrict__ W2, const float* __restrict__ b2) {
    const float inv_s2pi = 0.39894228040143267794f;
    float psi[KG];
#pragma unroll
    for (int k = 0; k < KG; k++) {
        float s = sg[k];
        float z = (x + bb[k] - mu[k]) / s;
        psi[k] = __expf(-0.5f * z * z) * (inv_s2pi / s);
    }
    float out = b2[0];
#pragma unroll
    for (int l = 0; l < KG; l++) {
        float a = b1[l];
#pragma unroll
        for (int k = 0; k < KG; k++) a += psi[k] * W1[l * KG + k];
        float g = 0.5f * a * (1.0f + erff(a * 0.70710678118654752440f));
        out += g * W2[l];
    }
    return out;
}

// ---------------------------------------------------------------------------
// Fused prepass:
//  ids [0, 2*TN)                 : bias interp tables (bf16 value | bf16 delta)
//  ids [2*TN, 2*TN+262144)       : Q,K f32 -> bf16 (float4 granularity)
//  ids [2*TN+262144, +524288)    : V -> bf16, transposed [h][d][s'] with the
//                                  k-permutation matching the P register order
// ---------------------------------------------------------------------------
#define QK4 262144              // (2*Hn*Sn*Dn)/4
#define VTN 524288              // Hn*Sn*Dn

__global__ __launch_bounds__(256) void prep_kernel(
    const float* __restrict__ Q, const float* __restrict__ K, const float* __restrict__ V,
    const float* __restrict__ muD, const float* __restrict__ sgD, const float* __restrict__ bD,
    const float* __restrict__ muE, const float* __restrict__ sgE, const float* __restrict__ bE,
    const float* __restrict__ W1, const float* __restrict__ b1,
    const float* __restrict__ W2, const float* __restrict__ b2,
    u32* __restrict__ tab, u16* __restrict__ Qb, u16* __restrict__ Kb, u16* __restrict__ VTi)
{
    int id = blockIdx.x * 256 + threadIdx.x;
    if (id < 2 * TN) {
        int which = (id >= TN);
        int idx = id & (TN - 1);
        float h = (which ? RE : RD) / (float)TN;
        float x0 = idx * h;
        float v0, v1;
        if (which) {
            v0 = bias_eval(x0,     muE, sgE, bE, W1, b1, W2, b2);
            v1 = bias_eval(x0 + h, muE, sgE, bE, W1, b1, W2, b2);
        } else {
            v0 = bias_eval(x0,     muD, sgD, bD, W1, b1, W2, b2);
            v1 = bias_eval(x0 + h, muD, sgD, bD, W1, b1, W2, b2);
        }
        tab[id] = (u32)f2bf(v0) | ((u32)f2bf(v1 - v0) << 16);
    } else if (id < 2 * TN + QK4) {
        int i = id - 2 * TN;
        int arr = i >> 17;          // 0 = Q, 1 = K
        i &= (1 << 17) - 1;
        float4 v = ((const float4*)(arr ? K : Q))[i];
        ushort4 o;
        o.x = f2bf(v.x); o.y = f2bf(v.y); o.z = f2bf(v.z); o.w = f2bf(v.w);
        ((ushort4*)(arr ? Kb : Qb))[i] = o;
    } else if (id < 2 * TN + QK4 + VTN) {
        int g = id - (2 * TN + QK4);
        int h = g >> 16;
        int d = (g >> 10) & 63;
        int s = g & 1023;
        int t = s >> 5, q = (s >> 3) & 3, j = s & 7;
        int src_s = (t << 5) + (q << 2) + (j & 3) + ((j >> 2) << 4);
        VTi[g] = f2bf(V[(((size_t)h << 10) + src_s) * Dn + d]);
    }
}

__device__ inline float lerp_tab(const u32* __restrict__ st, float x, float invh) {
    float tf = x * invh;
    int i = (int)tf;
    i = max(0, min(i, TN - 1));
    float fr = tf - (float)i;
    u32 p = st[i];
    return fmaf(bf2f((u16)(p >> 16)), fr, bf2f((u16)p));
}

// ---------------------------------------------------------------------------
// The heavy stream as a PURE elementwise map: fold Dm + Em + mask + both lerp
// tables into a row-major f16 array Cb[h][q][k]. Reads AND writes fully
// coalesced (thread g covers 8 consecutive k of one row). No dependencies,
// no MFMA register pressure, max occupancy -> this kernel can stream.
// ---------------------------------------------------------------------------
#define CB_GROUPS (Hn * Sn * Sn / 8)    // 1048576

__global__ __launch_bounds__(256) void bias_kernel(
    const float* __restrict__ Dm, const float* __restrict__ Em, const int* __restrict__ Mk,
    const u32* __restrict__ gtab, f16* __restrict__ Cb)
{
    __shared__ __align__(16) u32 sTab[2 * TN];      // 16 KB
    const int tid = threadIdx.x;
    {
        const uint4* g4 = (const uint4*)gtab;
        uint4* s4 = (uint4*)sTab;
#pragma unroll
        for (int i = 0; i < 4; i++) s4[tid + 256 * i] = g4[tid + 256 * i];
    }
    __syncthreads();
    const float invhD = (float)TN / RD;
    const float invhE = (float)TN / RE;

    for (int g = blockIdx.x * 256 + tid; g < CB_GROUPS; g += gridDim.x * 256) {
        const size_t base = (size_t)g * 8;

        const float4 d0 = *(const float4*)(Dm + base);
        const float4 d1 = *(const float4*)(Dm + base + 4);
        const float4 e0 = *(const float4*)(Em + base);
        const float4 e1 = *(const float4*)(Em + base + 4);
        const int4   m0 = *(const int4*)(Mk + base);
        const int4   m1 = *(const int4*)(Mk + base + 4);

        const float dv[8] = {d0.x, d0.y, d0.z, d0.w, d1.x, d1.y, d1.z, d1.w};
        const float ev[8] = {e0.x, e0.y, e0.z, e0.w, e1.x, e1.y, e1.z, e1.w};
        const int   mv[8] = {m0.x, m0.y, m0.z, m0.w, m1.x, m1.y, m1.z, m1.w};

        f16x8 o;
#pragma unroll
        for (int j = 0; j < 8; j++) {
            float b = lerp_tab(sTab, dv[j], invhD) + lerp_tab(sTab + TN, ev[j], invhE);
            // -60000 is exact in f16 and dominates qk*scale exactly like -1e9
            o[j] = (f16)((mv[j] == 0) ? -60000.0f : b);
        }
        ((f16x8*)Cb)[g] = o;
    }
}

// ---------------------------------------------------------------------------
// Lean fused flash attention, S^T formulation, k-split across blockIdx.z.
// All bias/mask work pre-folded into Cb: per tile only 10 loads
// (4 K + 4 V, both L2-resident; 2 x 8B Cb). No table, no lerp gathers.
// Grid (S/16, H, KS) = 2048 blocks; LDS = 17.9 KB epilogue only;
// launch_bounds(256,6) keeps VGPRs at ~84 (R5 lesson: (256,8)'s 32-VGPR
// squeeze serializes loads). Block writes one unnormalized partial
// (m, l, U); combine_kernel merges the KS=4 partials per q-row.
// ---------------------------------------------------------------------------
__global__ __launch_bounds__(256, 6) void attn_kernel(
    const u16* __restrict__ Qb, const u16* __restrict__ Kb, const u16* __restrict__ VTi,
    const f16* __restrict__ Cb,
    float* __restrict__ Up, float* __restrict__ Mp, float* __restrict__ Lp)
{
    __shared__ float sO[4][16][68];                 // padded: conflict-free epilogue
    __shared__ float sM[4][16], sL[4][16];

    const int tid  = threadIdx.x;
    const int h    = blockIdx.y;
    const int qb   = blockIdx.x;
    const int ks   = blockIdx.z;
    const int q0   = qb * 16;
    const int wave = tid >> 6;
    const int lane = tid & 63;
    const int quad = lane >> 4;
    const int l16  = lane & 15;

    const u16* Qh = Qb  + (size_t)h * Sn * Dn;
    const u16* Kh = Kb  + (size_t)h * Sn * Dn;
    const u16* Vh = VTi + (size_t)h * Dn * Sn;
    const f16* Ch = Cb  + ((size_t)h * Sn + (q0 + l16)) * Sn;
    const float scale = 0.08838834764831845f;       // 1/sqrt(2*64)

    // Persistent Q B-fragments: B[n=l16][k=quad*8+j], k = d-dim
    const bf16x8 bQ0 = *(const bf16x8*)(Qh + (q0 + l16) * Dn + quad * 8);
    const bf16x8 bQ1 = *(const bf16x8*)(Qh + (q0 + l16) * Dn + 32 + quad * 8);

    f32x4 O0 = {0.f, 0.f, 0.f, 0.f}, O1 = O0, O2 = O0, O3 = O0;
    float m_run = -1e30f, l_run = 0.f;

    for (int t = 0; t < 2; t++) {
        const int k0 = ks * 256 + wave * 64 + t * 32;

        // combined bias: one 8B f16x4 per accumulator register block
        const f16x4 C0 = *(const f16x4*)(Ch + k0 + quad * 4);
        const f16x4 C1 = *(const f16x4*)(Ch + k0 + 16 + quad * 4);

        const u16* kr = Kh + (size_t)(k0 + l16) * Dn + quad * 8;
        const bf16x8 aK00 = *(const bf16x8*)(kr);
        const bf16x8 aK01 = *(const bf16x8*)(kr + 32);
        const bf16x8 aK10 = *(const bf16x8*)(kr + 16 * Dn);
        const bf16x8 aK11 = *(const bf16x8*)(kr + 16 * Dn + 32);

        const u16* vr = Vh + k0 + quad * 8;
        const bf16x8 bV0 = *(const bf16x8*)(vr + (size_t)(l16)      * Sn);
        const bf16x8 bV1 = *(const bf16x8*)(vr + (size_t)(16 + l16) * Sn);
        const bf16x8 bV2 = *(const bf16x8*)(vr + (size_t)(32 + l16) * Sn);
        const bf16x8 bV3 = *(const bf16x8*)(vr + (size_t)(48 + l16) * Sn);

        f32x4 s0 = {0.f, 0.f, 0.f, 0.f}, s1 = s0;
        s0 = __builtin_amdgcn_mfma_f32_16x16x32_bf16(aK00, bQ0, s0, 0, 0, 0);
        s0 = __builtin_amdgcn_mfma_f32_16x16x32_bf16(aK01, bQ1, s0, 0, 0, 0);
        s1 = __builtin_amdgcn_mfma_f32_16x16x32_bf16(aK10, bQ0, s1, 0, 0, 0);
        s1 = __builtin_amdgcn_mfma_f32_16x16x32_bf16(aK11, bQ1, s1, 0, 0, 0);

        float sc0[4], sc1[4];
#pragma unroll
        for (int r = 0; r < 4; r++) {
            sc0[r] = fmaf(s0[r], scale, (float)C0[r]);
            sc1[r] = fmaf(s1[r], scale, (float)C1[r]);
        }

        // row max: local over 8 values, then across quads (2 shuffles)
        float mloc = fmaxf(fmaxf(fmaxf(sc0[0], sc0[1]), fmaxf(sc0[2], sc0[3])),
                           fmaxf(fmaxf(sc1[0], sc1[1]), fmaxf(sc1[2], sc1[3])));
        mloc = fmaxf(mloc, __shfl_xor(mloc, 16, 64));
        mloc = fmaxf(mloc, __shfl_xor(mloc, 32, 64));

        const float mn = fmaxf(m_run, mloc);
        const float al = __expf(m_run - mn);
        m_run = mn;

        float p0[4], p1[4], ll = 0.f;
#pragma unroll
        for (int r = 0; r < 4; r++) {
            p0[r] = __expf(sc0[r] - mn);
            p1[r] = __expf(sc1[r] - mn);
            ll += p0[r] + p1[r];
        }
        ll += __shfl_xor(ll, 16, 64);
        ll += __shfl_xor(ll, 32, 64);
        l_run = l_run * al + ll;

        // P A-fragment straight from registers (k-order matches permuted V)
        bf16x8 aP;
#pragma unroll
        for (int r = 0; r < 4; r++) {
            aP[r]     = (short)f2bf(p0[r]);
            aP[4 + r] = (short)f2bf(p1[r]);
        }

        // O rescale: alpha for row quad*4+r lives in lane (quad*4+r)
        const float a0 = __shfl(al, quad * 4 + 0, 64);
        const float a1 = __shfl(al, quad * 4 + 1, 64);
        const float a2 = __shfl(al, quad * 4 + 2, 64);
        const float a3 = __shfl(al, quad * 4 + 3, 64);
        O0[0] *= a0; O0[1] *= a1; O0[2] *= a2; O0[3] *= a3;
        O1[0] *= a0; O1[1] *= a1; O1[2] *= a2; O1[3] *= a3;
        O2[0] *= a0; O2[1] *= a1; O2[2] *= a2; O2[3] *= a3;
        O3[0] *= a0; O3[1] *= a1; O3[2] *= a2; O3[3] *= a3;

        O0 = __builtin_amdgcn_mfma_f32_16x16x32_bf16(aP, bV0, O0, 0, 0, 0);
        O1 = __builtin_amdgcn_mfma_f32_16x16x32_bf16(aP, bV1, O1, 0, 0, 0);
        O2 = __builtin_amdgcn_mfma_f32_16x16x32_bf16(aP, bV2, O2, 0, 0, 0);
        O3 = __builtin_amdgcn_mfma_f32_16x16x32_bf16(aP, bV3, O3, 0, 0, 0);
    }

    // cross-wave combine (flash-2): O regs are [row=quad*4+r][d=vt*16+l16]
    if (lane < 16) {
        sM[wave][lane] = m_run;
        sL[wave][lane] = l_run;
    }
#pragma unroll
    for (int r = 0; r < 4; r++) {
        sO[wave][quad * 4 + r][ 0 + l16] = O0[r];
        sO[wave][quad * 4 + r][16 + l16] = O1[r];
        sO[wave][quad * 4 + r][32 + l16] = O2[r];
        sO[wave][quad * 4 + r][48 + l16] = O3[r];
    }
    __syncthreads();

    // per-block partial: U = sum_w fac_w * O_w (UNNORMALIZED), plus (mg, lg)
    const int row = tid >> 4;
    const int c4  = (tid & 15) * 4;
    float mg = sM[0][row];
#pragma unroll
    for (int w = 1; w < 4; w++) mg = fmaxf(mg, sM[w][row]);
    float fac[4], lg = 0.f;
#pragma unroll
    for (int w = 0; w < 4; w++) {
        fac[w] = __expf(sM[w][row] - mg);
        lg += sL[w][row] * fac[w];
    }

    float acc[4];
#pragma unroll
    for (int c = 0; c < 4; c++) {
        acc[c] = 0.f;
#pragma unroll
        for (int w = 0; w < 4; w++) acc[c] += sO[w][row][c4 + c] * fac[w];
    }

    const int pb = (h * 64 + qb) * KS + ks;
    float4 ov = {acc[0], acc[1], acc[2], acc[3]};
    *(float4*)(Up + (size_t)pb * 1024 + row * 64 + c4) = ov;
    if ((tid & 15) == 0) {
        Mp[pb * 16 + row] = mg;
        Lp[pb * 16 + row] = lg;
    }
}

// ---------------------------------------------------------------------------
// Merge the KS=4 partials per q-row: M = max m_i; L = sum l_i e^{m_i-M};
// out = sum U_i e^{m_i-M} / L.  131072 threads, 16 threads/row.
// ---------------------------------------------------------------------------
__global__ __launch_bounds__(256) void combine_kernel(
    const float* __restrict__ Up, const float* __restrict__ Mp,
    const float* __restrict__ Lp, float* __restrict__ out)
{
    const int g  = blockIdx.x * 256 + threadIdx.x;
    const int r  = g >> 4;                 // global row 0..8191
    const int c4 = (g & 15) * 4;
    const int h  = r >> 10;
    const int s  = r & 1023;
    const int qb = s >> 4;
    const int r16 = s & 15;
    const int pb0 = (h * 64 + qb) * KS;

    float m[KS], l[KS];
#pragma unroll
    for (int k = 0; k < KS; k++) {
        m[k] = Mp[(pb0 + k) * 16 + r16];
        l[k] = Lp[(pb0 + k) * 16 + r16];
    }
    float M = m[0];
#pragma unroll
    for (int k = 1; k < KS; k++) M = fmaxf(M, m[k]);
    float f[KS], L = 0.f;
#pragma unroll
    for (int k = 0; k < KS; k++) {
        f[k] = __expf(m[k] - M);
        L += l[k] * f[k];
    }
    const float inv = 1.0f / L;

    float acc[4] = {0.f, 0.f, 0.f, 0.f};
#pragma unroll
    for (int k = 0; k < KS; k++) {
        const float4 u = *(const float4*)(Up + (size_t)(pb0 + k) * 1024 + r16 * 64 + c4);
        acc[0] += u.x * f[k]; acc[1] += u.y * f[k];
        acc[2] += u.z * f[k]; acc[3] += u.w * f[k];
    }
    float4 ov = {acc[0] * inv, acc[1] * inv, acc[2] * inv, acc[3] * inv};
    *(float4*)(out + (size_t)r * Dn + c4) = ov;
}

// ---------------------------------------------------------------------------
extern "C" void kernel_launch(void* const* d_in, const int* in_sizes, int n_in,
                              void* d_out, int out_size, void* d_ws, size_t ws_size,
                              hipStream_t stream) {
    const float* Q    = (const float*)d_in[0];
    const float* K    = (const float*)d_in[1];
    const float* V    = (const float*)d_in[2];
    const float* Dm   = (const float*)d_in[3];
    const float* Em   = (const float*)d_in[4];
    const int*   Mask = (const int*)d_in[5];
    const float* muD  = (const float*)d_in[6];
    const float* sgD  = (const float*)d_in[7];
    const float* bD   = (const float*)d_in[8];
    const float* muE  = (const float*)d_in[9];
    const float* sgE  = (const float*)d_in[10];
    const float* bE   = (const float*)d_in[11];
    const float* W1   = (const float*)d_in[12];
    const float* b1   = (const float*)d_in[13];
    const float* W2   = (const float*)d_in[14];
    const float* b2   = (const float*)d_in[15];

    // ws: tab 16KB | Qb/Kb/VTi 1MB each | Cb 16MB | Up 8.4MB | Mp,Lp 128KB each
    u32* tab = (u32*)d_ws;
    u16* Qb  = (u16*)((char*)d_ws + 2 * TN * 4);
    u16* Kb  = Qb + (size_t)Hn * Sn * Dn;
    u16* VTi = Kb + (size_t)Hn * Sn * Dn;
    f16* Cb  = (f16*)(VTi + (size_t)Hn * Sn * Dn);
    float* Up = (float*)(Cb + (size_t)Hn * Sn * Sn);
    float* Mp = Up + (size_t)Hn * 64 * KS * 16 * 64;
    float* Lp = Mp + (size_t)Hn * 64 * KS * 16;

    const int prep_threads = 2 * TN + QK4 + VTN;           // 790528
    prep_kernel<<<prep_threads / 256, 256, 0, stream>>>(
        Q, K, V, muD, sgD, bD, muE, sgE, bE, W1, b1, W2, b2,
        tab, Qb, Kb, VTi);

    bias_kernel<<<2048, 256, 0, stream>>>(Dm, Em, Mask, tab, Cb);

    dim3 grid(Sn / 16, Hn, KS);
    attn_kernel<<<grid, 256, 0, stream>>>(Qb, Kb, VTi, Cb, Up, Mp, Lp);

    combine_kernel<<<(Hn * Sn * 16) / 256, 256, 0, stream>>>(Up, Mp, Lp,
                                                             (float*)d_out);
}

// Round 7
// 185.764 us; speedup vs baseline: 1.0282x; 1.0160x over previous
//
#include <hip/hip_runtime.h>
#include <math.h>

// Shapes (fixed by the problem)
#define Hn 8
#define Sn 1024
#define Dn 64
#define KG 10

// Bias tables: dist in [0,10), energy in [0,5)
#define TN 2048
#define RD 10.25f
#define RE 5.125f

typedef __attribute__((ext_vector_type(8))) short bf16x8;
typedef __attribute__((ext_vector_type(4))) float f32x4;
typedef _Float16 f16;
typedef __attribute__((ext_vector_type(4))) _Float16 f16x4;
typedef __attribute__((ext_vector_type(8))) _Float16 f16x8;
typedef unsigned short u16;
typedef unsigned int u32;

__device__ inline float bf2f(u16 u) {
    union { u32 i; float f; } v;
    v.i = ((u32)u) << 16;
    return v.f;
}

__device__ inline u16 f2bf(float f) {
    union { float f; u32 i; } v;
    v.f = f;
    u32 i = v.i;
    return (u16)((i + 0x7FFFu + ((i >> 16) & 1u)) >> 16);   // RNE
}

// Fire-and-forget global->LDS DMA, 16 B per lane. No VGPR destination, so
// the register allocator cannot serialize these via anti-dependencies --
// the mechanism the compiler defeated in R2/R4 (named dbuf, sched_barrier).
// LDS dest is wave-uniform base + lane*16; readback at lane*16 is identity.
__device__ inline void stage16(const void* g, void* l) {
    __builtin_amdgcn_global_load_lds(
        (const __attribute__((address_space(1))) unsigned int*)g,
        (__attribute__((address_space(3))) unsigned int*)l,
        16, 0, 0);
}

// ---------------------------------------------------------------------------
// RBF (10 gaussians) -> 10x10 MLP (exact gelu) -> scalar, all f32.
// ---------------------------------------------------------------------------
__device__ float bias_eval(float x,
                           const float* __restrict__ mu, const float* __restrict__ sg,
                           const float* __restrict__ bb,
                           const float* __restrict__ W1, const float* __restrict__ b1,
                           const float* __restrict__ W2, const float* __restrict__ b2) {
    const float inv_s2pi = 0.39894228040143267794f;
    float psi[KG];
#pragma unroll
    for (int k = 0; k < KG; k++) {
        float s = sg[k];
        float z = (x + bb[k] - mu[k]) / s;
        psi[k] = __expf(-0.5f * z * z) * (inv_s2pi / s);
    }
    float out = b2[0];
#pragma unroll
    for (int l = 0; l < KG; l++) {
        float a = b1[l];
#pragma unroll
        for (int k = 0; k < KG; k++) a += psi[k] * W1[l * KG + k];
        float g = 0.5f * a * (1.0f + erff(a * 0.70710678118654752440f));
        out += g * W2[l];
    }
    return out;
}

// ---------------------------------------------------------------------------
// Fused prepass:
//  ids [0, 2*TN)                 : bias interp tables (bf16 value | bf16 delta)
//  ids [2*TN, 2*TN+262144)       : Q,K f32 -> bf16 (float4 granularity)
//  ids [2*TN+262144, +524288)    : V -> bf16, transposed [h][d][s'] with the
//                                  k-permutation matching the P register order
// ---------------------------------------------------------------------------
#define QK4 262144              // (2*Hn*Sn*Dn)/4
#define VTN 524288              // Hn*Sn*Dn

__global__ __launch_bounds__(256) void prep_kernel(
    const float* __restrict__ Q, const float* __restrict__ K, const float* __restrict__ V,
    const float* __restrict__ muD, const float* __restrict__ sgD, const float* __restrict__ bD,
    const float* __restrict__ muE, const float* __restrict__ sgE, const float* __restrict__ bE,
    const float* __restrict__ W1, const float* __restrict__ b1,
    const float* __restrict__ W2, const float* __restrict__ b2,
    u32* __restrict__ tab, u16* __restrict__ Qb, u16* __restrict__ Kb, u16* __restrict__ VTi)
{
    int id = blockIdx.x * 256 + threadIdx.x;
    if (id < 2 * TN) {
        int which = (id >= TN);
        int idx = id & (TN - 1);
        float h = (which ? RE : RD) / (float)TN;
        float x0 = idx * h;
        float v0, v1;
        if (which) {
            v0 = bias_eval(x0,     muE, sgE, bE, W1, b1, W2, b2);
            v1 = bias_eval(x0 + h, muE, sgE, bE, W1, b1, W2, b2);
        } else {
            v0 = bias_eval(x0,     muD, sgD, bD, W1, b1, W2, b2);
            v1 = bias_eval(x0 + h, muD, sgD, bD, W1, b1, W2, b2);
        }
        tab[id] = (u32)f2bf(v0) | ((u32)f2bf(v1 - v0) << 16);
    } else if (id < 2 * TN + QK4) {
        int i = id - 2 * TN;
        int arr = i >> 17;          // 0 = Q, 1 = K
        i &= (1 << 17) - 1;
        float4 v = ((const float4*)(arr ? K : Q))[i];
        ushort4 o;
        o.x = f2bf(v.x); o.y = f2bf(v.y); o.z = f2bf(v.z); o.w = f2bf(v.w);
        ((ushort4*)(arr ? Kb : Qb))[i] = o;
    } else if (id < 2 * TN + QK4 + VTN) {
        int g = id - (2 * TN + QK4);
        int h = g >> 16;
        int d = (g >> 10) & 63;
        int s = g & 1023;
        int t = s >> 5, q = (s >> 3) & 3, j = s & 7;
        int src_s = (t << 5) + (q << 2) + (j & 3) + ((j >> 2) << 4);
        VTi[g] = f2bf(V[(((size_t)h << 10) + src_s) * Dn + d]);
    }
}

__device__ inline float lerp_tab(const u32* __restrict__ st, float x, float invh) {
    float tf = x * invh;
    int i = (int)tf;
    i = max(0, min(i, TN - 1));
    float fr = tf - (float)i;
    u32 p = st[i];
    return fmaf(bf2f((u16)(p >> 16)), fr, bf2f((u16)p));
}

// ---------------------------------------------------------------------------
// The heavy stream as a PURE elementwise map: fold Dm + Em + mask + both lerp
// tables into a row-major f16 array Cb[h][q][k]. Reads AND writes fully
// coalesced; no dependencies, no MFMA register pressure -> streams at BW.
// ---------------------------------------------------------------------------
#define CB_GROUPS (Hn * Sn * Sn / 8)    // 1048576

__global__ __launch_bounds__(256) void bias_kernel(
    const float* __restrict__ Dm, const float* __restrict__ Em, const int* __restrict__ Mk,
    const u32* __restrict__ gtab, f16* __restrict__ Cb)
{
    __shared__ __align__(16) u32 sTab[2 * TN];      // 16 KB
    const int tid = threadIdx.x;
    {
        const uint4* g4 = (const uint4*)gtab;
        uint4* s4 = (uint4*)sTab;
#pragma unroll
        for (int i = 0; i < 4; i++) s4[tid + 256 * i] = g4[tid + 256 * i];
    }
    __syncthreads();
    const float invhD = (float)TN / RD;
    const float invhE = (float)TN / RE;

    for (int g = blockIdx.x * 256 + tid; g < CB_GROUPS; g += gridDim.x * 256) {
        const size_t base = (size_t)g * 8;

        const float4 d0 = *(const float4*)(Dm + base);
        const float4 d1 = *(const float4*)(Dm + base + 4);
        const float4 e0 = *(const float4*)(Em + base);
        const float4 e1 = *(const float4*)(Em + base + 4);
        const int4   m0 = *(const int4*)(Mk + base);
        const int4   m1 = *(const int4*)(Mk + base + 4);

        const float dv[8] = {d0.x, d0.y, d0.z, d0.w, d1.x, d1.y, d1.z, d1.w};
        const float ev[8] = {e0.x, e0.y, e0.z, e0.w, e1.x, e1.y, e1.z, e1.w};
        const int   mv[8] = {m0.x, m0.y, m0.z, m0.w, m1.x, m1.y, m1.z, m1.w};

        f16x8 o;
#pragma unroll
        for (int j = 0; j < 8; j++) {
            float b = lerp_tab(sTab, dv[j], invhD) + lerp_tab(sTab + TN, ev[j], invhE);
            // -60000 is exact in f16 and dominates qk*scale exactly like -1e9
            o[j] = (f16)((mv[j] == 0) ? -60000.0f : b);
        }
        ((f16x8*)Cb)[g] = o;
    }
}

// ---------------------------------------------------------------------------
// Fused flash attention, S^T formulation, KS=1 (no k-split, no combine pass).
// Per tile, ALL eight 16B/lane K/V loads go through global_load_lds into a
// private 8 KB LDS region per wave: they issue back-to-back as DMA (no VGPR
// anti-deps -> cannot be re-serialized by RA), one s_waitcnt vmcnt(0) per
// tile pays ONE memory latency instead of 8-10 (R0-R5 failure mode).
// Readback is identity: fragment for lane = staged bytes at lane*16.
// Epilogue (flash-2 cross-wave combine) reuses the staging LDS after a
// barrier; output written directly, normalized.
// ---------------------------------------------------------------------------
__global__ __launch_bounds__(256) void attn_kernel(
    const u16* __restrict__ Qb, const u16* __restrict__ Kb, const u16* __restrict__ VTi,
    const f16* __restrict__ Cb, float* __restrict__ out)
{
    __shared__ __align__(16) char sBuf[4 * 8 * 1024];   // 32 KB: staging, then sO
    __shared__ float sM[4][16], sL[4][16];

    const int tid  = threadIdx.x;
    const int h    = blockIdx.y;
    const int q0   = blockIdx.x * 16;
    const int wave = tid >> 6;
    const int lane = tid & 63;
    const int quad = lane >> 4;
    const int l16  = lane & 15;

    const u16* Qh = Qb  + (size_t)h * Sn * Dn;
    const u16* Kh = Kb  + (size_t)h * Sn * Dn;
    const u16* Vh = VTi + (size_t)h * Dn * Sn;
    const f16* Ch = Cb  + ((size_t)h * Sn + (q0 + l16)) * Sn;
    const float scale = 0.08838834764831845f;       // 1/sqrt(2*64)

    // Persistent Q B-fragments: B[n=l16][k=quad*8+j], k = d-dim
    const bf16x8 bQ0 = *(const bf16x8*)(Qh + (q0 + l16) * Dn + quad * 8);
    const bf16x8 bQ1 = *(const bf16x8*)(Qh + (q0 + l16) * Dn + 32 + quad * 8);

    char* st = sBuf + wave * 8192;          // wave-private staging (8 chunks x 1 KB)

    f32x4 O0 = {0.f, 0.f, 0.f, 0.f}, O1 = O0, O2 = O0, O3 = O0;
    float m_run = -1e30f, l_run = 0.f;

    for (int t = 0; t < 8; t++) {
        const int k0 = wave * 256 + t * 32;

        // -------- stage all 8 K/V chunks: fire-and-forget DMA --------
        const u16* kr = Kh + (size_t)(k0 + l16) * Dn + quad * 8;
        const u16* vr = Vh + k0 + quad * 8 + (size_t)l16 * Sn;
        stage16(kr,               st);
        stage16(kr + 32,          st + 1024);
        stage16(kr + 16 * Dn,     st + 2048);
        stage16(kr + 16 * Dn + 32,st + 3072);
        stage16(vr,               st + 4096);
        stage16(vr + 16 * Sn,     st + 5120);
        stage16(vr + 32 * Sn,     st + 6144);
        stage16(vr + 48 * Sn,     st + 7168);

        // combined bias: two plain 8 B loads (latency hides under vmcnt wait)
        const f16x4 C0 = *(const f16x4*)(Ch + k0 + quad * 4);
        const f16x4 C1 = *(const f16x4*)(Ch + k0 + 16 + quad * 4);

        asm volatile("s_waitcnt vmcnt(0)" ::: "memory");

        // identity readback: this lane's fragments at lane*16
        const char* ls = st + lane * 16;
        const bf16x8 aK00 = *(const bf16x8*)(ls);
        const bf16x8 aK01 = *(const bf16x8*)(ls + 1024);
        const bf16x8 aK10 = *(const bf16x8*)(ls + 2048);
        const bf16x8 aK11 = *(const bf16x8*)(ls + 3072);
        const bf16x8 bV0  = *(const bf16x8*)(ls + 4096);
        const bf16x8 bV1  = *(const bf16x8*)(ls + 5120);
        const bf16x8 bV2  = *(const bf16x8*)(ls + 6144);
        const bf16x8 bV3  = *(const bf16x8*)(ls + 7168);

        f32x4 s0 = {0.f, 0.f, 0.f, 0.f}, s1 = s0;
        s0 = __builtin_amdgcn_mfma_f32_16x16x32_bf16(aK00, bQ0, s0, 0, 0, 0);
        s0 = __builtin_amdgcn_mfma_f32_16x16x32_bf16(aK01, bQ1, s0, 0, 0, 0);
        s1 = __builtin_amdgcn_mfma_f32_16x16x32_bf16(aK10, bQ0, s1, 0, 0, 0);
        s1 = __builtin_amdgcn_mfma_f32_16x16x32_bf16(aK11, bQ1, s1, 0, 0, 0);

        float sc0[4], sc1[4];
#pragma unroll
        for (int r = 0; r < 4; r++) {
            sc0[r] = fmaf(s0[r], scale, (float)C0[r]);
            sc1[r] = fmaf(s1[r], scale, (float)C1[r]);
        }

        // row max: local over 8 values, then across quads (2 shuffles)
        float mloc = fmaxf(fmaxf(fmaxf(sc0[0], sc0[1]), fmaxf(sc0[2], sc0[3])),
                           fmaxf(fmaxf(sc1[0], sc1[1]), fmaxf(sc1[2], sc1[3])));
        mloc = fmaxf(mloc, __shfl_xor(mloc, 16, 64));
        mloc = fmaxf(mloc, __shfl_xor(mloc, 32, 64));

        const float mn = fmaxf(m_run, mloc);
        const float al = __expf(m_run - mn);
        m_run = mn;

        float p0[4], p1[4], ll = 0.f;
#pragma unroll
        for (int r = 0; r < 4; r++) {
            p0[r] = __expf(sc0[r] - mn);
            p1[r] = __expf(sc1[r] - mn);
            ll += p0[r] + p1[r];
        }
        ll += __shfl_xor(ll, 16, 64);
        ll += __shfl_xor(ll, 32, 64);
        l_run = l_run * al + ll;

        // P A-fragment straight from registers (k-order matches permuted V)
        bf16x8 aP;
#pragma unroll
        for (int r = 0; r < 4; r++) {
            aP[r]     = (short)f2bf(p0[r]);
            aP[4 + r] = (short)f2bf(p1[r]);
        }

        // O rescale: alpha for row quad*4+r lives in lane (quad*4+r)
        const float a0 = __shfl(al, quad * 4 + 0, 64);
        const float a1 = __shfl(al, quad * 4 + 1, 64);
        const float a2 = __shfl(al, quad * 4 + 2, 64);
        const float a3 = __shfl(al, quad * 4 + 3, 64);
        O0[0] *= a0; O0[1] *= a1; O0[2] *= a2; O0[3] *= a3;
        O1[0] *= a0; O1[1] *= a1; O1[2] *= a2; O1[3] *= a3;
        O2[0] *= a0; O2[1] *= a1; O2[2] *= a2; O2[3] *= a3;
        O3[0] *= a0; O3[1] *= a1; O3[2] *= a2; O3[3] *= a3;

        O0 = __builtin_amdgcn_mfma_f32_16x16x32_bf16(aP, bV0, O0, 0, 0, 0);
        O1 = __builtin_amdgcn_mfma_f32_16x16x32_bf16(aP, bV1, O1, 0, 0, 0);
        O2 = __builtin_amdgcn_mfma_f32_16x16x32_bf16(aP, bV2, O2, 0, 0, 0);
        O3 = __builtin_amdgcn_mfma_f32_16x16x32_bf16(aP, bV3, O3, 0, 0, 0);

        // order this tile's LDS reads before next tile's DMA overwrites
        asm volatile("" ::: "memory");
    }

    // all waves done with staging regions before sO overlays them
    __syncthreads();

    float (*sO)[16][68] = (float (*)[16][68])sBuf;  // 17.4 KB < 32 KB
    if (lane < 16) {
        sM[wave][lane] = m_run;
        sL[wave][lane] = l_run;
    }
#pragma unroll
    for (int r = 0; r < 4; r++) {
        sO[wave][quad * 4 + r][ 0 + l16] = O0[r];
        sO[wave][quad * 4 + r][16 + l16] = O1[r];
        sO[wave][quad * 4 + r][32 + l16] = O2[r];
        sO[wave][quad * 4 + r][48 + l16] = O3[r];
    }
    __syncthreads();

    const int row = tid >> 4;
    const int c4  = (tid & 15) * 4;
    float mg = sM[0][row];
#pragma unroll
    for (int w = 1; w < 4; w++) mg = fmaxf(mg, sM[w][row]);
    float fac[4], lg = 0.f;
#pragma unroll
    for (int w = 0; w < 4; w++) {
        fac[w] = __expf(sM[w][row] - mg);
        lg += sL[w][row] * fac[w];
    }
    const float inv = 1.0f / lg;

    float acc[4];
#pragma unroll
    for (int c = 0; c < 4; c++) {
        acc[c] = 0.f;
#pragma unroll
        for (int w = 0; w < 4; w++) acc[c] += sO[w][row][c4 + c] * fac[w];
        acc[c] *= inv;
    }
    float4 ov = {acc[0], acc[1], acc[2], acc[3]};
    *(float4*)(out + ((size_t)(h * Sn + q0 + row)) * Dn + c4) = ov;
}

// ---------------------------------------------------------------------------
extern "C" void kernel_launch(void* const* d_in, const int* in_sizes, int n_in,
                              void* d_out, int out_size, void* d_ws, size_t ws_size,
                              hipStream_t stream) {
    const float* Q    = (const float*)d_in[0];
    const float* K    = (const float*)d_in[1];
    const float* V    = (const float*)d_in[2];
    const float* Dm   = (const float*)d_in[3];
    const float* Em   = (const float*)d_in[4];
    const int*   Mask = (const int*)d_in[5];
    const float* muD  = (const float*)d_in[6];
    const float* sgD  = (const float*)d_in[7];
    const float* bD   = (const float*)d_in[8];
    const float* muE  = (const float*)d_in[9];
    const float* sgE  = (const float*)d_in[10];
    const float* bE   = (const float*)d_in[11];
    const float* W1   = (const float*)d_in[12];
    const float* b1   = (const float*)d_in[13];
    const float* W2   = (const float*)d_in[14];
    const float* b2   = (const float*)d_in[15];

    // ws: tab 16KB | Qb/Kb/VTi 1MB each | Cb 16MB  (~19.1 MB total)
    u32* tab = (u32*)d_ws;
    u16* Qb  = (u16*)((char*)d_ws + 2 * TN * 4);
    u16* Kb  = Qb + (size_t)Hn * Sn * Dn;
    u16* VTi = Kb + (size_t)Hn * Sn * Dn;
    f16* Cb  = (f16*)(VTi + (size_t)Hn * Sn * Dn);

    const int prep_threads = 2 * TN + QK4 + VTN;           // 790528
    prep_kernel<<<prep_threads / 256, 256, 0, stream>>>(
        Q, K, V, muD, sgD, bD, muE, sgE, bE, W1, b1, W2, b2,
        tab, Qb, Kb, VTi);

    bias_kernel<<<2048, 256, 0, stream>>>(Dm, Em, Mask, tab, Cb);

    dim3 grid(Sn / 16, Hn);
    attn_kernel<<<grid, 256, 0, stream>>>(Qb, Kb, VTi, Cb, (float*)d_out);
}

// Round 8
// 173.034 us; speedup vs baseline: 1.1039x; 1.0736x over previous
//
#include <hip/hip_runtime.h>
#include <math.h>

// Shapes (fixed by the problem)
#define Hn 8
#define Sn 1024
#define Dn 64
#define KG 10

// Bias tables: dist in [0,10), energy in [0,5)
#define TN 2048
#define RD 10.25f
#define RE 5.125f

typedef __attribute__((ext_vector_type(8))) short bf16x8;
typedef __attribute__((ext_vector_type(4))) float f32x4;
typedef unsigned short u16;
typedef unsigned int u32;

__device__ inline float bf2f(u16 u) {
    union { u32 i; float f; } v;
    v.i = ((u32)u) << 16;
    return v.f;
}

__device__ inline u16 f2bf(float f) {
    union { float f; u32 i; } v;
    v.f = f;
    u32 i = v.i;
    return (u16)((i + 0x7FFFu + ((i >> 16) & 1u)) >> 16);   // RNE
}

// Fire-and-forget global->LDS DMA, 16 B per lane. No VGPR destination ->
// the register allocator cannot re-serialize these (R7 confirmed: this is
// the one clustering mechanism hipcc does not defeat). LDS dest is
// wave-uniform base + lane*16; global src is per-lane; readback at lane*16
// is the identity for every chunk (K, V, D, E, M alike).
__device__ inline void stage16(const void* g, void* l) {
    __builtin_amdgcn_global_load_lds(
        (const __attribute__((address_space(1))) unsigned int*)g,
        (__attribute__((address_space(3))) unsigned int*)l,
        16, 0, 0);
}

// ---------------------------------------------------------------------------
// RBF (10 gaussians) -> 10x10 MLP (exact gelu) -> scalar, all f32.
// ---------------------------------------------------------------------------
__device__ float bias_eval(float x,
                           const float* __restrict__ mu, const float* __restrict__ sg,
                           const float* __restrict__ bb,
                           const float* __restrict__ W1, const float* __restrict__ b1,
                           const float* __restrict__ W2, const float* __restrict__ b2) {
    const float inv_s2pi = 0.39894228040143267794f;
    float psi[KG];
#pragma unroll
    for (int k = 0; k < KG; k++) {
        float s = sg[k];
        float z = (x + bb[k] - mu[k]) / s;
        psi[k] = __expf(-0.5f * z * z) * (inv_s2pi / s);
    }
    float out = b2[0];
#pragma unroll
    for (int l = 0; l < KG; l++) {
        float a = b1[l];
#pragma unroll
        for (int k = 0; k < KG; k++) a += psi[k] * W1[l * KG + k];
        float g = 0.5f * a * (1.0f + erff(a * 0.70710678118654752440f));
        out += g * W2[l];
    }
    return out;
}

// ---------------------------------------------------------------------------
// Fused prepass:
//  ids [0, 2*TN)                 : bias interp tables (bf16 value | bf16 delta)
//  ids [2*TN, 2*TN+262144)       : Q,K f32 -> bf16 (float4 granularity)
//  ids [2*TN+262144, +524288)    : V -> bf16, transposed [h][d][s'] with the
//                                  k-permutation matching the P register order
// ---------------------------------------------------------------------------
#define QK4 262144              // (2*Hn*Sn*Dn)/4
#define VTN 524288              // Hn*Sn*Dn

__global__ __launch_bounds__(256) void prep_kernel(
    const float* __restrict__ Q, const float* __restrict__ K, const float* __restrict__ V,
    const float* __restrict__ muD, const float* __restrict__ sgD, const float* __restrict__ bD,
    const float* __restrict__ muE, const float* __restrict__ sgE, const float* __restrict__ bE,
    const float* __restrict__ W1, const float* __restrict__ b1,
    const float* __restrict__ W2, const float* __restrict__ b2,
    u32* __restrict__ tab, u16* __restrict__ Qb, u16* __restrict__ Kb, u16* __restrict__ VTi)
{
    int id = blockIdx.x * 256 + threadIdx.x;
    if (id < 2 * TN) {
        int which = (id >= TN);
        int idx = id & (TN - 1);
        float h = (which ? RE : RD) / (float)TN;
        float x0 = idx * h;
        float v0, v1;
        if (which) {
            v0 = bias_eval(x0,     muE, sgE, bE, W1, b1, W2, b2);
            v1 = bias_eval(x0 + h, muE, sgE, bE, W1, b1, W2, b2);
        } else {
            v0 = bias_eval(x0,     muD, sgD, bD, W1, b1, W2, b2);
            v1 = bias_eval(x0 + h, muD, sgD, bD, W1, b1, W2, b2);
        }
        tab[id] = (u32)f2bf(v0) | ((u32)f2bf(v1 - v0) << 16);
    } else if (id < 2 * TN + QK4) {
        int i = id - 2 * TN;
        int arr = i >> 17;          // 0 = Q, 1 = K
        i &= (1 << 17) - 1;
        float4 v = ((const float4*)(arr ? K : Q))[i];
        ushort4 o;
        o.x = f2bf(v.x); o.y = f2bf(v.y); o.z = f2bf(v.z); o.w = f2bf(v.w);
        ((ushort4*)(arr ? Kb : Qb))[i] = o;
    } else if (id < 2 * TN + QK4 + VTN) {
        int g = id - (2 * TN + QK4);
        int h = g >> 16;
        int d = (g >> 10) & 63;
        int s = g & 1023;
        int t = s >> 5, q = (s >> 3) & 3, j = s & 7;
        int src_s = (t << 5) + (q << 2) + (j & 3) + ((j >> 2) << 4);
        VTi[g] = f2bf(V[(((size_t)h << 10) + src_s) * Dn + d]);
    }
}

__device__ inline float lerp_tab(const u32* __restrict__ st, float x, float invh) {
    float tf = x * invh;
    int i = (int)tf;
    i = max(0, min(i, TN - 1));
    float fr = tf - (float)i;
    u32 p = st[i];
    return fmaf(bf2f((u16)(p >> 16)), fr, bf2f((u16)p));
}

// ---------------------------------------------------------------------------
// Fully fused flash attention, S^T formulation. Per tile ALL 14 input chunks
// (4 K + 4 V + 2 Dm + 2 Em + 2 Mask, 16 B/lane each) are staged via
// global_load_lds DMA into a private 14 KB region per wave -- they issue
// back-to-back (R7-verified mechanism), one s_waitcnt vmcnt(0) per tile pays
// ONE memory latency instead of 14. No Cb intermediate (R1/R5-R7's 32 MB
// round-trip deleted), D/E/M streamed exactly once from HBM, bias lerped
// from the 16 KB LDS table as in R0.
// LDS: 16 KB table + 56 KB staging + eps = 74 KB -> 2 blocks/CU, 8 waves/CU;
// in-flight/CU = 8 waves x 14 KB = 112 KB >> Little's-law need for ~5 TB/s.
// Epilogue overlays sO on the staging buffer after a barrier.
// ---------------------------------------------------------------------------
#define STW 14336               // staging bytes per wave

__global__ __launch_bounds__(256) void attn_kernel(
    const u16* __restrict__ Qb, const u16* __restrict__ Kb, const u16* __restrict__ VTi,
    const float* __restrict__ Dm, const float* __restrict__ Em, const int* __restrict__ Mk,
    const u32* __restrict__ gtab, float* __restrict__ out)
{
    __shared__ __align__(16) u32 sTab[2 * TN];      // 16 KB, persistent
    __shared__ __align__(16) char sBuf[4 * STW];    // 56 KB staging, then sO
    __shared__ float sM[4][16], sL[4][16];

    const int tid = threadIdx.x;
    {   // stage tables: 1024 uint4 over 256 threads
        const uint4* g4 = (const uint4*)gtab;
        uint4* s4 = (uint4*)sTab;
#pragma unroll
        for (int i = 0; i < 4; i++) s4[tid + 256 * i] = g4[tid + 256 * i];
    }
    __syncthreads();

    const int h    = blockIdx.y;
    const int q0   = blockIdx.x * 16;
    const int wave = tid >> 6;
    const int lane = tid & 63;
    const int quad = lane >> 4;
    const int l16  = lane & 15;

    const u16* Qh = Qb  + (size_t)h * Sn * Dn;
    const u16* Kh = Kb  + (size_t)h * Sn * Dn;
    const u16* Vh = VTi + (size_t)h * Dn * Sn;
    const float* Dh = Dm + (size_t)h * Sn * Sn + (size_t)(q0 + l16) * Sn;
    const float* Eh = Em + (size_t)h * Sn * Sn + (size_t)(q0 + l16) * Sn;
    const int*   Mh = Mk + (size_t)h * Sn * Sn + (size_t)(q0 + l16) * Sn;
    const float invhD = (float)TN / RD;
    const float invhE = (float)TN / RE;
    const float scale = 0.08838834764831845f;       // 1/sqrt(2*64)

    // Persistent Q B-fragments: B[n=l16][k=quad*8+j], k = d-dim
    const bf16x8 bQ0 = *(const bf16x8*)(Qh + (q0 + l16) * Dn + quad * 8);
    const bf16x8 bQ1 = *(const bf16x8*)(Qh + (q0 + l16) * Dn + 32 + quad * 8);

    char* st = sBuf + wave * STW;       // wave-private staging (14 x 1 KB)

    f32x4 O0 = {0.f, 0.f, 0.f, 0.f}, O1 = O0, O2 = O0, O3 = O0;
    float m_run = -1e30f, l_run = 0.f;

    for (int t = 0; t < 8; t++) {
        const int k0 = wave * 256 + t * 32;

        // ---- stage all 14 chunks: fire-and-forget DMA, no VGPR dests ----
        const u16* kr = Kh + (size_t)(k0 + l16) * Dn + quad * 8;
        const u16* vr = Vh + k0 + quad * 8 + (size_t)l16 * Sn;
        const float* dr = Dh + k0 + quad * 4;
        const float* er = Eh + k0 + quad * 4;
        const int*   mr = Mh + k0 + quad * 4;
        stage16(kr,                st);
        stage16(kr + 32,           st + 1024);
        stage16(kr + 16 * Dn,      st + 2048);
        stage16(kr + 16 * Dn + 32, st + 3072);
        stage16(vr,                st + 4096);
        stage16(vr + 16 * Sn,      st + 5120);
        stage16(vr + 32 * Sn,      st + 6144);
        stage16(vr + 48 * Sn,      st + 7168);
        stage16(dr,                st + 8192);
        stage16(dr + 16,           st + 9216);
        stage16(er,                st + 10240);
        stage16(er + 16,           st + 11264);
        stage16(mr,                st + 12288);
        stage16(mr + 16,           st + 13312);

        asm volatile("s_waitcnt vmcnt(0)" ::: "memory");

        // identity readback: this lane's data at lane*16 in each chunk
        const char* ls = st + lane * 16;
        const bf16x8 aK00 = *(const bf16x8*)(ls);
        const bf16x8 aK01 = *(const bf16x8*)(ls + 1024);
        const bf16x8 aK10 = *(const bf16x8*)(ls + 2048);
        const bf16x8 aK11 = *(const bf16x8*)(ls + 3072);
        const bf16x8 bV0  = *(const bf16x8*)(ls + 4096);
        const bf16x8 bV1  = *(const bf16x8*)(ls + 5120);
        const bf16x8 bV2  = *(const bf16x8*)(ls + 6144);
        const bf16x8 bV3  = *(const bf16x8*)(ls + 7168);
        const float4 Dv0  = *(const float4*)(ls + 8192);
        const float4 Dv1  = *(const float4*)(ls + 9216);
        const float4 Ev0  = *(const float4*)(ls + 10240);
        const float4 Ev1  = *(const float4*)(ls + 11264);
        const int4   Mv0  = *(const int4*)(ls + 12288);
        const int4   Mv1  = *(const int4*)(ls + 13312);

        // pin the LDS reads above before any later DMA can overwrite them
        asm volatile("" ::: "memory");

        f32x4 s0 = {0.f, 0.f, 0.f, 0.f}, s1 = s0;
        s0 = __builtin_amdgcn_mfma_f32_16x16x32_bf16(aK00, bQ0, s0, 0, 0, 0);
        s0 = __builtin_amdgcn_mfma_f32_16x16x32_bf16(aK01, bQ1, s0, 0, 0, 0);
        s1 = __builtin_amdgcn_mfma_f32_16x16x32_bf16(aK10, bQ0, s1, 0, 0, 0);
        s1 = __builtin_amdgcn_mfma_f32_16x16x32_bf16(aK11, bQ1, s1, 0, 0, 0);

        const float dv0[4] = {Dv0.x, Dv0.y, Dv0.z, Dv0.w};
        const float dv1[4] = {Dv1.x, Dv1.y, Dv1.z, Dv1.w};
        const float ev0[4] = {Ev0.x, Ev0.y, Ev0.z, Ev0.w};
        const float ev1[4] = {Ev1.x, Ev1.y, Ev1.z, Ev1.w};
        const int   mv0[4] = {Mv0.x, Mv0.y, Mv0.z, Mv0.w};
        const int   mv1[4] = {Mv1.x, Mv1.y, Mv1.z, Mv1.w};

        float sc0[4], sc1[4];
#pragma unroll
        for (int r = 0; r < 4; r++) {
            float v0 = s0[r] * scale + lerp_tab(sTab, dv0[r], invhD)
                                     + lerp_tab(sTab + TN, ev0[r], invhE);
            v0 = fminf(fmaxf(v0, -80.f), 80.f);
            sc0[r] = (mv0[r] == 0) ? -1e9f : v0;
            float v1 = s1[r] * scale + lerp_tab(sTab, dv1[r], invhD)
                                     + lerp_tab(sTab + TN, ev1[r], invhE);
            v1 = fminf(fmaxf(v1, -80.f), 80.f);
            sc1[r] = (mv1[r] == 0) ? -1e9f : v1;
        }

        // row max: local over 8 values, then across quads (2 shuffles)
        float mloc = fmaxf(fmaxf(fmaxf(sc0[0], sc0[1]), fmaxf(sc0[2], sc0[3])),
                           fmaxf(fmaxf(sc1[0], sc1[1]), fmaxf(sc1[2], sc1[3])));
        mloc = fmaxf(mloc, __shfl_xor(mloc, 16, 64));
        mloc = fmaxf(mloc, __shfl_xor(mloc, 32, 64));

        const float mn = fmaxf(m_run, mloc);
        const float al = __expf(m_run - mn);
        m_run = mn;

        float p0[4], p1[4], ll = 0.f;
#pragma unroll
        for (int r = 0; r < 4; r++) {
            p0[r] = __expf(sc0[r] - mn);
            p1[r] = __expf(sc1[r] - mn);
            ll += p0[r] + p1[r];
        }
        ll += __shfl_xor(ll, 16, 64);
        ll += __shfl_xor(ll, 32, 64);
        l_run = l_run * al + ll;

        // P A-fragment straight from registers (k-order matches permuted V)
        bf16x8 aP;
#pragma unroll
        for (int r = 0; r < 4; r++) {
            aP[r]     = (short)f2bf(p0[r]);
            aP[4 + r] = (short)f2bf(p1[r]);
        }

        // O rescale: alpha for row quad*4+r lives in lane (quad*4+r)
        const float a0 = __shfl(al, quad * 4 + 0, 64);
        const float a1 = __shfl(al, quad * 4 + 1, 64);
        const float a2 = __shfl(al, quad * 4 + 2, 64);
        const float a3 = __shfl(al, quad * 4 + 3, 64);
        O0[0] *= a0; O0[1] *= a1; O0[2] *= a2; O0[3] *= a3;
        O1[0] *= a0; O1[1] *= a1; O1[2] *= a2; O1[3] *= a3;
        O2[0] *= a0; O2[1] *= a1; O2[2] *= a2; O2[3] *= a3;
        O3[0] *= a0; O3[1] *= a1; O3[2] *= a2; O3[3] *= a3;

        O0 = __builtin_amdgcn_mfma_f32_16x16x32_bf16(aP, bV0, O0, 0, 0, 0);
        O1 = __builtin_amdgcn_mfma_f32_16x16x32_bf16(aP, bV1, O1, 0, 0, 0);
        O2 = __builtin_amdgcn_mfma_f32_16x16x32_bf16(aP, bV2, O2, 0, 0, 0);
        O3 = __builtin_amdgcn_mfma_f32_16x16x32_bf16(aP, bV3, O3, 0, 0, 0);
    }

    // all waves done with staging before sO overlays it
    __syncthreads();

    float (*sO)[16][68] = (float (*)[16][68])sBuf;  // 17.4 KB < 56 KB
    if (lane < 16) {
        sM[wave][lane] = m_run;
        sL[wave][lane] = l_run;
    }
#pragma unroll
    for (int r = 0; r < 4; r++) {
        sO[wave][quad * 4 + r][ 0 + l16] = O0[r];
        sO[wave][quad * 4 + r][16 + l16] = O1[r];
        sO[wave][quad * 4 + r][32 + l16] = O2[r];
        sO[wave][quad * 4 + r][48 + l16] = O3[r];
    }
    __syncthreads();

    const int row = tid >> 4;
    const int c4  = (tid & 15) * 4;
    float mg = sM[0][row];
#pragma unroll
    for (int w = 1; w < 4; w++) mg = fmaxf(mg, sM[w][row]);
    float fac[4], lg = 0.f;
#pragma unroll
    for (int w = 0; w < 4; w++) {
        fac[w] = __expf(sM[w][row] - mg);
        lg += sL[w][row] * fac[w];
    }
    const float inv = 1.0f / lg;

    float acc[4];
#pragma unroll
    for (int c = 0; c < 4; c++) {
        acc[c] = 0.f;
#pragma unroll
        for (int w = 0; w < 4; w++) acc[c] += sO[w][row][c4 + c] * fac[w];
        acc[c] *= inv;
    }
    float4 ov = {acc[0], acc[1], acc[2], acc[3]};
    *(float4*)(out + ((size_t)(h * Sn + q0 + row)) * Dn + c4) = ov;
}

// ---------------------------------------------------------------------------
extern "C" void kernel_launch(void* const* d_in, const int* in_sizes, int n_in,
                              void* d_out, int out_size, void* d_ws, size_t ws_size,
                              hipStream_t stream) {
    const float* Q    = (const float*)d_in[0];
    const float* K    = (const float*)d_in[1];
    const float* V    = (const float*)d_in[2];
    const float* Dm   = (const float*)d_in[3];
    const float* Em   = (const float*)d_in[4];
    const int*   Mask = (const int*)d_in[5];
    const float* muD  = (const float*)d_in[6];
    const float* sgD  = (const float*)d_in[7];
    const float* bD   = (const float*)d_in[8];
    const float* muE  = (const float*)d_in[9];
    const float* sgE  = (const float*)d_in[10];
    const float* bE   = (const float*)d_in[11];
    const float* W1   = (const float*)d_in[12];
    const float* b1   = (const float*)d_in[13];
    const float* W2   = (const float*)d_in[14];
    const float* b2   = (const float*)d_in[15];

    // ws layout: tab 16 KB | Qb 1 MB | Kb 1 MB | VTi 1 MB  (~3.1 MB total)
    u32* tab = (u32*)d_ws;
    u16* Qb  = (u16*)((char*)d_ws + 2 * TN * 4);
    u16* Kb  = Qb + (size_t)Hn * Sn * Dn;
    u16* VTi = Kb + (size_t)Hn * Sn * Dn;

    const int prep_threads = 2 * TN + QK4 + VTN;           // 790528
    prep_kernel<<<prep_threads / 256, 256, 0, stream>>>(
        Q, K, V, muD, sgD, bD, muE, sgE, bE, W1, b1, W2, b2,
        tab, Qb, Kb, VTi);

    dim3 grid(Sn / 16, Hn);
    attn_kernel<<<grid, 256, 0, stream>>>(Qb, Kb, VTi, Dm, Em, Mask, tab,
                                          (float*)d_out);
}